// Round 5
// baseline (191.163 us; speedup 1.0000x reference)
//
#include <hip/hip_runtime.h>

typedef unsigned int u32;
typedef unsigned long long u64;
typedef unsigned short u16;

#define NL 2048

typedef __attribute__((ext_vector_type(8))) short bf16x8;
typedef __attribute__((ext_vector_type(16))) float f32x16;

__device__ __forceinline__ u16 to_bf16(float f) {
  u32 b = __float_as_uint(f);
  b += 0x7FFFu + ((b >> 16) & 1u);
  return (u16)(b >> 16);
}

__device__ __forceinline__ void gload_lds16(const void* g, void* l) {
  __builtin_amdgcn_global_load_lds(
      (const __attribute__((address_space(1))) u32*)g,
      (__attribute__((address_space(3))) u32*)l, 16, 0, 0);
}

// full ascending bitonic sort of 64 u32 across the wave (1 per lane)
__device__ __forceinline__ u32 sort64_u32(u32 v, int lane) {
#pragma unroll
  for (int k = 2; k <= 64; k <<= 1) {
#pragma unroll
    for (int j = k >> 1; j > 0; j >>= 1) {
      u32 p = (u32)__shfl_xor((int)v, j, 64);
      bool lower = ((lane & j) == 0);
      bool asc = ((lane & k) == 0);
      u32 lo = v < p ? v : p;
      u32 hi = v < p ? p : v;
      v = (lower == asc) ? lo : hi;
    }
  }
  return v;
}

// ---------------------------------------------------------------------------
// Kernel A+P: exact 32-NN (rank-select, fixed-unroll fast path) + weight prep.
// grid = 2059 x 512 threads (bx<2048: knn; 2048-2057: opW transpose;
// 2058: embW transpose + head packing).
// ---------------------------------------------------------------------------
__global__ __launch_bounds__(512) void knn_prep_kernel(
    const float* __restrict__ frames, int* __restrict__ idx32,
    const float* __restrict__ opW, const float* __restrict__ embW,
    const float* __restrict__ betaW, const float* __restrict__ sattW,
    const float* __restrict__ cattW, const float* __restrict__ nodW,
    const float* __restrict__ betaB, const float* __restrict__ sattB,
    const float* __restrict__ cattB, const float* __restrict__ nodB,
    u16* __restrict__ opWt, u16* __restrict__ embWt, float* __restrict__ w5,
    float* __restrict__ b5) {
  __shared__ union U {
    struct {
      float4 cand[2048];
      u64 comp[8][256];
    } k;
    float tp[128 * 73];
  } sm;
  const int bx = blockIdx.x;
  const int tid = threadIdx.x;

  if (bx >= 2048) {
    if (bx < 2058) {
      const int k0 = (bx - 2048) * 64;
#pragma unroll
      for (int j = 0; j < 4; j++) {
        int f = tid + j * 512;
        int kk = f >> 5;
        int o4 = (f & 31) * 4;
        float4 v = *(const float4*)(opW + (size_t)(k0 + kk) * 128 + o4);
        sm.tp[(o4 + 0) * 73 + kk] = v.x;
        sm.tp[(o4 + 1) * 73 + kk] = v.y;
        sm.tp[(o4 + 2) * 73 + kk] = v.z;
        sm.tp[(o4 + 3) * 73 + kk] = v.w;
      }
      __syncthreads();
      u32* ow = (u32*)opWt;
#pragma unroll
      for (int j = 0; j < 8; j++) {
        int f = tid + j * 512;
        int o = f >> 5, q = f & 31;
        float lo = sm.tp[o * 73 + q * 2];
        float hi = sm.tp[o * 73 + q * 2 + 1];
        ow[o * 320 + (k0 >> 1) + q] = (u32)to_bf16(lo) | ((u32)to_bf16(hi) << 16);
      }
    } else {
      for (int f = tid; f < 4096; f += 512) {
        int j = f >> 7, kk = f & 127;
        embWt[f] = to_bf16(embW[(size_t)kk * 32 + j]);
      }
      if (tid < 160) {
        int h = tid >> 5, j = tid & 31;
        float v = (h == 0) ? betaW[j]
                  : (h == 1) ? sattW[j]
                  : (h == 2) ? cattW[j]
                  : (h == 3) ? nodW[j * 2]
                             : nodW[j * 2 + 1];
        w5[j * 8 + h] = v;
      } else if (tid < 165) {
        int h = tid - 160;
        float v = (h == 0) ? betaB[0]
                  : (h == 1) ? sattB[0]
                  : (h == 2) ? cattB[0]
                  : (h == 3) ? nodB[0]
                             : nodB[1];
        b5[h] = v;
      }
    }
    return;
  }

  const int w = tid >> 6, lane = tid & 63;
  const int query = bx * 8 + w;
  const int b = query >> 11, lq = query & (NL - 1);

#pragma unroll
  for (int i = 0; i < 4; i++) {
    int l = tid + i * 512;
    const float* fp = frames + (size_t)(b * NL + l) * 12;
    float4 fr = *(const float4*)fp;
    sm.k.cand[l] = make_float4(fr.x, fr.y, fr.z,
                               fr.x * fr.x + fr.y * fr.y + fr.z * fr.z);
  }
  __syncthreads();

  float4 me = sm.k.cand[lq];
  u32 k[32];
  u32 m = 0xFFFFFFFFu;
#pragma unroll
  for (int i = 0; i < 32; i++) {
    float4 c = sm.k.cand[i * 64 + lane];
    float dot = c.x * me.x + c.y * me.y + c.z * me.z;
    float d2 = (me.w + c.w) - 2.0f * dot;
    u32 kb = __float_as_uint(d2);
    u32 key = kb ^ ((u32)((int)kb >> 31) | 0x80000000u);
    k[i] = key;
    m = key < m ? key : m;
  }

  u32 ms = sort64_u32(m, lane);
  u32 T0 = (u32)__shfl((int)ms, 31, 64);

  int base = 0;
#pragma unroll
  for (int i = 0; i < 32; i++) {
    bool flag = (k[i] <= T0);
    u64 mask = __ballot(flag);
    if (flag) {
      u32 rank = __builtin_amdgcn_mbcnt_hi(
          (u32)(mask >> 32), __builtin_amdgcn_mbcnt_lo((u32)mask, 0u));
      int pos = base + (int)rank;
      if (pos < 256) sm.k.comp[w][pos] = ((u64)k[i] << 32) | (u32)(i * 64 + lane);
    }
    base += (int)__popcll(mask);
  }
  int cnt = base < 256 ? base : 256;
  __syncthreads();  // uniform: orders in-wave LDS writes before reads

  if (cnt <= 64) {
    // fast path: pad to 64, fully-unrolled (pipelined) rank count.
    int pz = cnt + lane;
    if (pz < 64) sm.k.comp[w][pz] = ~0ull;
    u64 e0 = sm.k.comp[w][lane];
    int r0 = 0;
#pragma unroll
    for (int mi = 0; mi < 64; mi++) {
      u64 em = sm.k.comp[w][mi];
      r0 += (em < e0) ? 1 : 0;
    }
    // pad lanes have e0=~0 -> r0 = cnt >= 32 -> no write
    if (r0 < 32) idx32[(size_t)query * 32 + r0] = (int)(e0 & 0xFFFFFFFFull);
  } else {
    // generic exact path (validated round 4); ~never taken
    for (int b0 = 0; b0 < cnt; b0 += 64) {
      bool live = (b0 + lane < cnt);
      u64 e = live ? sm.k.comp[w][b0 + lane] : ~0ull;
      int r = 0;
      for (int mi = 0; mi < cnt; mi++) {
        u64 em = sm.k.comp[w][mi];
        r += (em < e) ? 1 : 0;
      }
      if (live && r < 32)
        idx32[(size_t)query * 32 + r] = (int)(e & 0xFFFFFFFFull);
    }
  }
}

// ---------------------------------------------------------------------------
// Kernel BC: fused stage-1 + GEMM. grid = 512 (32 pts x 128 outs), block =
// 256 (4 waves). Each wave runs the stage-1 body 8x (pts w*8+it), writing
// the outer product as bf16 straight into the swizzled LDS A-tile (byte
// layout identical to round-4's global_load_lds staging). Then the validated
// MFMA loop (B-frags from L2-resident opWt) + epilogue.
// smem map: [0,40960) A-tile | [40960,43008) sCoord | [43008,48128) sAttrN.
// Epilogue reuses [0,32768) after the post-MFMA barrier.
// head8 layout per point: [catt, nf0, nf1, -, beta, satt, -, -]
// ---------------------------------------------------------------------------
__global__ __launch_bounds__(256) void s1gemm_kernel(
    const float* __restrict__ frames, const float* __restrict__ attrs,
    const int* __restrict__ aaidx, const float* __restrict__ cen1,
    const float* __restrict__ prec1, const int* __restrict__ idx32,
    const u16* __restrict__ opWt, const float* __restrict__ opB,
    const u16* __restrict__ embWt, const float* __restrict__ embB,
    const float* __restrict__ w5, const float* __restrict__ b5,
    float* __restrict__ head8) {
  __shared__ __align__(16) char smem[49152];
  float* sCoord = (float*)(smem + 40960);  // [4][16][8]
  float* sAttrN = (float*)(smem + 43008);  // [4][16][20] n-major
  const int tid = threadIdx.x;
  const int w = tid >> 6, lane = tid & 63;
  const int p0 = blockIdx.x * 32;  // 32 | 2048 -> whole tile in one batch
  const int g = lane & 31, nh = lane >> 5;

  float pr[7][7], cn[7];
#pragma unroll
  for (int d = 0; d < 7; d++) {
    cn[d] = cen1[d * 32 + g];
#pragma unroll
    for (int kk = 0; kk < 7; kk++) pr[d][kk] = prec1[(d * 7 + kk) * 32 + g];
  }

  for (int it = 0; it < 8; it++) {
    __syncthreads();  // protects sCoord/sAttrN reuse across iterations
    const int m = w * 8 + it;
    const int pid = p0 + m;
    const int b = pid >> 11;
    if (lane < 16) {
      int n = lane;
      int j = idx32[pid * 32 + n];
      int jg = b * NL + j;
      const float* fs = frames + (size_t)pid * 12;
      const float* fj = frames + (size_t)jg * 12;
      float4 A0 = *(const float4*)(fs);
      float4 A1 = *(const float4*)(fs + 4);
      float4 A2 = *(const float4*)(fs + 8);
      float4 B0 = *(const float4*)(fj);
      float4 B2 = *(const float4*)(fj + 8);
      float dx = B0.x - A0.x, dy = B0.y - A0.y, dzc = B0.z - A0.z;
      float a0x = A0.w, a0y = A1.x, a0z = A1.y;
      float a1x = A1.z, a1y = A1.w, a1z = A2.x;
      float a2x = A2.y, a2y = A2.z, a2z = A2.w;  // z_i == axes[2]
      float zjx = B2.y, zjy = B2.z, zjz = B2.w;
      float dd = dx * dx + dy * dy + dzc * dzc + 1e-12f;
      float dist = sqrtf(dd);
      float e0 = dx * a0x + dy * a0y + dzc * a0z;
      float e1 = dx * a1x + dy * a1y + dzc * a1z;
      float e2 = dx * a2x + dy * a2y + dzc * a2z;
      float zz = a2x * zjx + a2y * zjy + a2z * zjz;
      float dzv = (dx * zjx + dy * zjy + dzc * zjz) / dist;
      float zdv = (a2x * dx + a2y * dy + a2z * dzc) / dist;
      float si = (float)aaidx[pid];
      float sj = (float)aaidx[jg];
      float idist = fminf(fabsf(sj - si), 8.0f);
      float* cr = sCoord + w * 128 + n * 8;
      cr[0] = e0; cr[1] = e1; cr[2] = e2; cr[3] = idist;
      cr[4] = zz; cr[5] = dzv; cr[6] = zdv;
      const float* ar = attrs + (size_t)jg * 20;
      float* aw = sAttrN + w * 320 + n * 20;
      *(float4*)(aw + 0) = *(const float4*)(ar + 0);
      *(float4*)(aw + 4) = *(const float4*)(ar + 4);
      *(float4*)(aw + 8) = *(const float4*)(ar + 8);
      *(float4*)(aw + 12) = *(const float4*)(ar + 12);
      *(float4*)(aw + 16) = *(const float4*)(ar + 16);
    }
    __syncthreads();
    // gauss + outer accumulate: lane (g, nh) covers n = nh*8..nh*8+8
    float partial[20];
#pragma unroll
    for (int h = 0; h < 20; h++) partial[h] = 0.f;
#pragma unroll
    for (int q = 0; q < 8; q++) {
      int n = nh * 8 + q;
      const float* cr = sCoord + w * 128 + n * 8;
      float4 c0 = *(const float4*)(cr);
      float4 c1 = *(const float4*)(cr + 4);
      float df[7] = {c0.x - cn[0], c0.y - cn[1], c0.z - cn[2], c0.w - cn[3],
                     c1.x - cn[4], c1.y - cn[5], c1.z - cn[6]};
      float s = 0.0f;
#pragma unroll
      for (int kk = 0; kk < 7; kk++) {
        float y = 0.0f;
#pragma unroll
        for (int d = 0; d < 7; d++) y = fmaf(df[d], pr[d][kk], y);
        s = fmaf(y, y, s);
      }
      float gval = __expf(-0.5f * s);
      const float* ar = sAttrN + w * 320 + n * 20;
      float4 a0 = *(const float4*)(ar + 0);
      float4 a1 = *(const float4*)(ar + 4);
      float4 a2 = *(const float4*)(ar + 8);
      float4 a3 = *(const float4*)(ar + 12);
      float4 a4 = *(const float4*)(ar + 16);
      float av[20] = {a0.x, a0.y, a0.z, a0.w, a1.x, a1.y, a1.z, a1.w,
                      a2.x, a2.y, a2.z, a2.w, a3.x, a3.y, a3.z, a3.w,
                      a4.x, a4.y, a4.z, a4.w};
#pragma unroll
      for (int h = 0; h < 20; h++) partial[h] = fmaf(gval, av[h], partial[h]);
    }
#pragma unroll
    for (int h = 0; h < 20; h++)
      partial[h] += __shfl_xor(partial[h], 32, 64);
    // write 10 bf16 (5 u32) to the swizzled A-tile; nh picks the h-half
#pragma unroll
    for (int i = 0; i < 5; i++) {
      int h = nh * 10 + i * 2;
      int o = g * 20 + h;
      int cc = o >> 6, G = (o >> 3) & 7, e = o & 7;
      u32 pk = (u32)to_bf16(partial[h]) | ((u32)to_bf16(partial[h + 1]) << 16);
      *(u32*)(smem + cc * 4096 + m * 128 + ((G ^ (m & 7)) << 4) + e * 2) = pk;
    }
  }
  __syncthreads();  // all A-tile writes visible to all waves

  // ---- MFMA main loop (round-4 validated addressing) ----
  const int m2 = lane & 31, kh = lane >> 5;
  f32x16 acc;
#pragma unroll
  for (int r = 0; r < 16; r++) acc[r] = 0.f;
  const u16* gB = opWt + (size_t)(w * 32 + m2) * 640;
#pragma unroll
  for (int cc = 0; cc < 10; cc++) {
#pragma unroll
    for (int s = 0; s < 4; s++) {
      int pg = (s * 2 + kh) ^ (m2 & 7);
      bf16x8 av = *(bf16x8*)(smem + cc * 4096 + m2 * 128 + pg * 16);
      bf16x8 bv = *(const bf16x8*)(gB + cc * 64 + s * 16 + kh * 8);
      acc = __builtin_amdgcn_mfma_f32_32x32x16_bf16(av, bv, acc, 0, 0, 0);
    }
  }
  __syncthreads();  // A reads done before fTile overwrites smem[0..8K)

  // ---- epilogue (round-4 verbatim) ----
  const int o = w * 32 + m2;
  float bo = opB[o];
#pragma unroll
  for (int i = 0; i < 2; i++) {
    int j = w * 8 + i * 4 + (lane >> 4);
    int ge = (lane & 15) ^ (j & 7);
    gload_lds16(embWt + j * 128 + ge * 8, smem + 8192 + w * 2048 + i * 1024);
  }
  u16* sFb = (u16*)smem;
#pragma unroll
  for (int r = 0; r < 16; r++) {
    int mm = (r & 3) + 8 * (r >> 2) + 4 * kh;
    float v = fmaxf(acc[r] + bo, 0.f);
    int pg = (o >> 3) ^ (mm & 7);
    sFb[mm * 128 + pg * 8 + (o & 7)] = to_bf16(v);
  }
  __syncthreads();

  f32x16 acc2;
#pragma unroll
  for (int r = 0; r < 16; r++) acc2[r] = 0.f;
#pragma unroll
  for (int t2 = 0; t2 < 2; t2++) {
    int gg = (w * 2 + t2) * 2 + kh;
    int pg = gg ^ (m2 & 7);
    bf16x8 av = *(bf16x8*)(smem + m2 * 256 + pg * 16);
    bf16x8 bv = *(bf16x8*)(smem + 8192 + m2 * 256 + pg * 16);
    acc2 = __builtin_amdgcn_mfma_f32_32x32x16_bf16(av, bv, acc2, 0, 0, 0);
  }
  float* scr = (float*)(smem + 16384) + w * 1024;
#pragma unroll
  for (int r = 0; r < 16; r++) {
    int mm = (r & 3) + 8 * (r >> 2) + 4 * kh;
    scr[mm * 32 + m2] = acc2[r];
  }
  __syncthreads();

  {
    float* sc = (float*)(smem + 16384);
    int i4 = tid * 4;
    float4 v0 = *(float4*)(sc + i4);
    float4 v1 = *(float4*)(sc + 1024 + i4);
    float4 v2 = *(float4*)(sc + 2048 + i4);
    float4 v3 = *(float4*)(sc + 3072 + i4);
    int pp = tid >> 3, j0 = (tid & 7) * 4;
    float4 eb = *(const float4*)(embB + j0);
    float4 e;
    e.x = fmaxf(v0.x + v1.x + v2.x + v3.x + eb.x, 0.f);
    e.y = fmaxf(v0.y + v1.y + v2.y + v3.y + eb.y, 0.f);
    e.z = fmaxf(v0.z + v1.z + v2.z + v3.z + eb.z, 0.f);
    e.w = fmaxf(v0.w + v1.w + v2.w + v3.w + eb.w, 0.f);
    *(float4*)((float*)smem + pp * 36 + j0) = e;
  }
  __syncthreads();

  if (tid < 160) {
    int h = tid >> 5, p = tid & 31;
    const float* sE = (const float*)smem + p * 36;
    float a = b5[h];
#pragma unroll
    for (int j = 0; j < 32; j++) a = fmaf(sE[j], w5[j * 8 + h], a);
    a = fmaxf(a, 0.f);
    int slot = (h < 2) ? (h + 4) : (h - 2);
    head8[(size_t)(p0 + p) * 8 + slot] = a;
  }
}

// ---------------------------------------------------------------------------
// Kernel E: stage-2 (unchanged from round 4 — validated)
// ---------------------------------------------------------------------------
__global__ __launch_bounds__(256) void stage2_kernel(
    const float* __restrict__ frames, const int* __restrict__ aaidx,
    const float* __restrict__ cen2, const float* __restrict__ prec2,
    const float* __restrict__ emb2W, const float* __restrict__ emb2B,
    const int* __restrict__ idx32, const float* __restrict__ head8,
    float* __restrict__ out) {
  __shared__ float sCoord[4 * 32 * 5];
  __shared__ float sG2[4 * 32 * 33];
  const int tid = threadIdx.x;
  const int pt = tid >> 6, lane = tid & 63;
  const int pid = blockIdx.x * 4 + pt;
  const int b = pid >> 11;
  const int g = lane & 31;

  float pr[5][5], cn[5];
#pragma unroll
  for (int d = 0; d < 5; d++) {
    cn[d] = cen2[d * 32 + g];
#pragma unroll
    for (int kk = 0; kk < 5; kk++) pr[d][kk] = prec2[(d * 5 + kk) * 32 + g];
  }

  float4 hv = make_float4(0.f, 0.f, 0.f, 0.f);
  float betaS = 0.f, sattS = 0.f;
  if (lane < 32) {
    int n = lane;
    int j = idx32[pid * 32 + n];
    int jg = b * NL + j;
    const float* fs = frames + (size_t)pid * 12;
    const float* fj = frames + (size_t)jg * 12;
    float4 A0 = *(const float4*)(fs);
    float4 A2 = *(const float4*)(fs + 8);
    float4 B0 = *(const float4*)(fj);
    float4 B2 = *(const float4*)(fj + 8);
    float dx = B0.x - A0.x, dy = B0.y - A0.y, dzc = B0.z - A0.z;
    float a2x = A2.y, a2y = A2.z, a2z = A2.w;  // z_i
    float zjx = B2.y, zjy = B2.z, zjz = B2.w;
    float dd = dx * dx + dy * dy + dzc * dzc + 1e-12f;
    float dist = sqrtf(dd);
    float zz = a2x * zjx + a2y * zjy + a2z * zjz;
    float dzv = (dx * zjx + dy * zjy + dzc * zjz) / dist;
    float zdv = (a2x * dx + a2y * dy + a2z * dzc) / dist;
    float si = (float)aaidx[pid];
    float sj = (float)aaidx[jg];
    float idist = fminf(fabsf(sj - si), 8.0f);
    float* cr = sCoord + pt * 160 + n * 5;
    cr[0] = dist; cr[1] = zz; cr[2] = dzv; cr[3] = zdv; cr[4] = idist;
    hv = *(const float4*)(head8 + (size_t)jg * 8);
    betaS = head8[(size_t)pid * 8 + 4];
    sattS = head8[(size_t)pid * 8 + 5];
  }
  __syncthreads();
  {
    const int nh = lane >> 5;
#pragma unroll
    for (int i = 0; i < 16; i++) {
      int n = nh * 16 + i;
      const float* cr = sCoord + pt * 160 + n * 5;
      float df[5];
#pragma unroll
      for (int d = 0; d < 5; d++) df[d] = cr[d] - cn[d];
      float s = 0.0f;
#pragma unroll
      for (int kk = 0; kk < 5; kk++) {
        float y = 0.0f;
#pragma unroll
        for (int d = 0; d < 5; d++) y = fmaf(df[d], pr[d][kk], y);
        s = fmaf(y, y, s);
      }
      sG2[pt * 1056 + n * 33 + g] = __expf(-0.5f * s);
    }
  }
  __syncthreads();
  if (lane < 32) {
    int n = lane;
    float gw = emb2B[0];
#pragma unroll 8
    for (int gg = 0; gg < 32; gg++)
      gw = fmaf(sG2[pt * 1056 + n * 33 + gg], emb2W[gg], gw);
    gw = fmaxf(gw, 0.0f);
    float e = (n == 0) ? sattS : hv.x;
    float logit = betaS * e;
    float mx = logit;
#pragma unroll
    for (int d = 1; d < 32; d <<= 1) mx = fmaxf(mx, __shfl_xor(mx, d, 64));
    float wv = gw * __expf(logit - mx);
    float S = wv;
#pragma unroll
    for (int d = 1; d < 32; d <<= 1) S += __shfl_xor(S, d, 64);
    float a = wv / (S + 1e-6f);
    float o0 = a * hv.y, o1 = a * hv.z;
#pragma unroll
    for (int d = 1; d < 32; d <<= 1) {
      o0 += __shfl_xor(o0, d, 64);
      o1 += __shfl_xor(o1, d, 64);
    }
    if (n == 0) {
      out[pid * 2 + 0] = o0;
      out[pid * 2 + 1] = o1;
    }
  }
}

// ---------------------------------------------------------------------------
extern "C" void kernel_launch(void* const* d_in, const int* in_sizes, int n_in,
                              void* d_out, int out_size, void* d_ws, size_t ws_size,
                              hipStream_t stream) {
  const float* attrs = (const float*)d_in[0];
  const float* frames = (const float*)d_in[1];
  const int* aaidx = (const int*)d_in[2];
  const float* cen1 = (const float*)d_in[3];
  const float* prec1 = (const float*)d_in[4];
  const float* opW = (const float*)d_in[5];
  const float* opB = (const float*)d_in[6];
  const float* embW = (const float*)d_in[7];
  const float* embB = (const float*)d_in[8];
  const float* betaW = (const float*)d_in[9];
  const float* betaB = (const float*)d_in[10];
  const float* sattW = (const float*)d_in[11];
  const float* sattB = (const float*)d_in[12];
  const float* cattW = (const float*)d_in[13];
  const float* cattB = (const float*)d_in[14];
  const float* nodW = (const float*)d_in[15];
  const float* nodB = (const float*)d_in[16];
  const float* cen2 = (const float*)d_in[17];
  const float* prec2 = (const float*)d_in[18];
  const float* emb2W = (const float*)d_in[19];
  const float* emb2B = (const float*)d_in[20];
  float* out = (float*)d_out;

  char* ws = (char*)d_ws;
  int* idx32 = (int*)ws;                    // 2 MiB
  float* head8 = (float*)(ws + 2097152);    // 512 KiB
  u16* opWt = (u16*)(ws + 2621440);         // 160 KiB
  u16* embWt = (u16*)(ws + 2785280);        // 8 KiB
  float* w5 = (float*)(ws + 2793472);       // 1 KiB
  float* b5 = (float*)(ws + 2794496);       // 32 B

  knn_prep_kernel<<<dim3(2059), dim3(512), 0, stream>>>(
      frames, idx32, opW, embW, betaW, sattW, cattW, nodW, betaB, sattB,
      cattB, nodB, opWt, embWt, w5, b5);
  s1gemm_kernel<<<dim3(512), dim3(256), 0, stream>>>(
      frames, attrs, aaidx, cen1, prec1, idx32, opWt, opB, embWt, embB, w5,
      b5, head8);
  stage2_kernel<<<dim3(4096), dim3(256), 0, stream>>>(frames, aaidx, cen2, prec2,
                                                      emb2W, emb2B, idx32, head8, out);
}

// Round 6
// 184.047 us; speedup vs baseline: 1.0387x; 1.0387x over previous
//
#include <hip/hip_runtime.h>

typedef unsigned int u32;
typedef unsigned long long u64;
typedef unsigned short u16;

#define NL 2048

typedef __attribute__((ext_vector_type(8))) short bf16x8;
typedef __attribute__((ext_vector_type(16))) float f32x16;

__device__ __forceinline__ u16 to_bf16(float f) {
  u32 b = __float_as_uint(f);
  b += 0x7FFFu + ((b >> 16) & 1u);
  return (u16)(b >> 16);
}

__device__ __forceinline__ void gload_lds16(const void* g, void* l) {
  __builtin_amdgcn_global_load_lds(
      (const __attribute__((address_space(1))) u32*)g,
      (__attribute__((address_space(3))) u32*)l, 16, 0, 0);
}

// full ascending bitonic sort of 64 u32 across the wave (1 per lane)
__device__ __forceinline__ u32 sort64_u32(u32 v, int lane) {
#pragma unroll
  for (int k = 2; k <= 64; k <<= 1) {
#pragma unroll
    for (int j = k >> 1; j > 0; j >>= 1) {
      u32 p = (u32)__shfl_xor((int)v, j, 64);
      bool lower = ((lane & j) == 0);
      bool asc = ((lane & k) == 0);
      u32 lo = v < p ? v : p;
      u32 hi = v < p ? p : v;
      v = (lower == asc) ? lo : hi;
    }
  }
  return v;
}

// ---------------------------------------------------------------------------
// Kernel A+P: exact 32-NN (rank-select, fixed-unroll fast path) + weight prep.
// grid = 2059 x 512 threads (bx<2048: knn; 2048-2057: opW transpose;
// 2058: embW transpose + head packing).  [validated round 5]
// ---------------------------------------------------------------------------
__global__ __launch_bounds__(512) void knn_prep_kernel(
    const float* __restrict__ frames, int* __restrict__ idx32,
    const float* __restrict__ opW, const float* __restrict__ embW,
    const float* __restrict__ betaW, const float* __restrict__ sattW,
    const float* __restrict__ cattW, const float* __restrict__ nodW,
    const float* __restrict__ betaB, const float* __restrict__ sattB,
    const float* __restrict__ cattB, const float* __restrict__ nodB,
    u16* __restrict__ opWt, u16* __restrict__ embWt, float* __restrict__ w5,
    float* __restrict__ b5) {
  __shared__ union U {
    struct {
      float4 cand[2048];
      u64 comp[8][256];
    } k;
    float tp[128 * 73];
  } sm;
  const int bx = blockIdx.x;
  const int tid = threadIdx.x;

  if (bx >= 2048) {
    if (bx < 2058) {
      const int k0 = (bx - 2048) * 64;
#pragma unroll
      for (int j = 0; j < 4; j++) {
        int f = tid + j * 512;
        int kk = f >> 5;
        int o4 = (f & 31) * 4;
        float4 v = *(const float4*)(opW + (size_t)(k0 + kk) * 128 + o4);
        sm.tp[(o4 + 0) * 73 + kk] = v.x;
        sm.tp[(o4 + 1) * 73 + kk] = v.y;
        sm.tp[(o4 + 2) * 73 + kk] = v.z;
        sm.tp[(o4 + 3) * 73 + kk] = v.w;
      }
      __syncthreads();
      u32* ow = (u32*)opWt;
#pragma unroll
      for (int j = 0; j < 8; j++) {
        int f = tid + j * 512;
        int o = f >> 5, q = f & 31;
        float lo = sm.tp[o * 73 + q * 2];
        float hi = sm.tp[o * 73 + q * 2 + 1];
        ow[o * 320 + (k0 >> 1) + q] = (u32)to_bf16(lo) | ((u32)to_bf16(hi) << 16);
      }
    } else {
      for (int f = tid; f < 4096; f += 512) {
        int j = f >> 7, kk = f & 127;
        embWt[f] = to_bf16(embW[(size_t)kk * 32 + j]);
      }
      if (tid < 160) {
        int h = tid >> 5, j = tid & 31;
        float v = (h == 0) ? betaW[j]
                  : (h == 1) ? sattW[j]
                  : (h == 2) ? cattW[j]
                  : (h == 3) ? nodW[j * 2]
                             : nodW[j * 2 + 1];
        w5[j * 8 + h] = v;
      } else if (tid < 165) {
        int h = tid - 160;
        float v = (h == 0) ? betaB[0]
                  : (h == 1) ? sattB[0]
                  : (h == 2) ? cattB[0]
                  : (h == 3) ? nodB[0]
                             : nodB[1];
        b5[h] = v;
      }
    }
    return;
  }

  const int w = tid >> 6, lane = tid & 63;
  const int query = bx * 8 + w;
  const int b = query >> 11, lq = query & (NL - 1);

#pragma unroll
  for (int i = 0; i < 4; i++) {
    int l = tid + i * 512;
    const float* fp = frames + (size_t)(b * NL + l) * 12;
    float4 fr = *(const float4*)fp;
    sm.k.cand[l] = make_float4(fr.x, fr.y, fr.z,
                               fr.x * fr.x + fr.y * fr.y + fr.z * fr.z);
  }
  __syncthreads();

  float4 me = sm.k.cand[lq];
  u32 k[32];
  u32 m = 0xFFFFFFFFu;
#pragma unroll
  for (int i = 0; i < 32; i++) {
    float4 c = sm.k.cand[i * 64 + lane];
    float dot = c.x * me.x + c.y * me.y + c.z * me.z;
    float d2 = (me.w + c.w) - 2.0f * dot;
    u32 kb = __float_as_uint(d2);
    u32 key = kb ^ ((u32)((int)kb >> 31) | 0x80000000u);
    k[i] = key;
    m = key < m ? key : m;
  }

  u32 ms = sort64_u32(m, lane);
  u32 T0 = (u32)__shfl((int)ms, 31, 64);

  int base = 0;
#pragma unroll
  for (int i = 0; i < 32; i++) {
    bool flag = (k[i] <= T0);
    u64 mask = __ballot(flag);
    if (flag) {
      u32 rank = __builtin_amdgcn_mbcnt_hi(
          (u32)(mask >> 32), __builtin_amdgcn_mbcnt_lo((u32)mask, 0u));
      int pos = base + (int)rank;
      if (pos < 256) sm.k.comp[w][pos] = ((u64)k[i] << 32) | (u32)(i * 64 + lane);
    }
    base += (int)__popcll(mask);
  }
  int cnt = base < 256 ? base : 256;
  __syncthreads();  // uniform: orders in-wave LDS writes before reads

  if (cnt <= 64) {
    // fast path: pad to 64, fully-unrolled (pipelined) rank count.
    int pz = cnt + lane;
    if (pz < 64) sm.k.comp[w][pz] = ~0ull;
    u64 e0 = sm.k.comp[w][lane];
    int r0 = 0;
#pragma unroll
    for (int mi = 0; mi < 64; mi++) {
      u64 em = sm.k.comp[w][mi];
      r0 += (em < e0) ? 1 : 0;
    }
    if (r0 < 32) idx32[(size_t)query * 32 + r0] = (int)(e0 & 0xFFFFFFFFull);
  } else {
    // generic exact path; ~never taken
    for (int b0 = 0; b0 < cnt; b0 += 64) {
      bool live = (b0 + lane < cnt);
      u64 e = live ? sm.k.comp[w][b0 + lane] : ~0ull;
      int r = 0;
      for (int mi = 0; mi < cnt; mi++) {
        u64 em = sm.k.comp[w][mi];
        r += (em < e) ? 1 : 0;
      }
      if (live && r < 32)
        idx32[(size_t)query * 32 + r] = (int)(e & 0xFFFFFFFFull);
    }
  }
}

// ---------------------------------------------------------------------------
// Kernel B: stage-1 coords + gaussians + outer product -> bf16 outer[p][640]
// block = 256 (4 points x 64 lanes), grid = 4096.  [validated round 4]
// ---------------------------------------------------------------------------
__global__ __launch_bounds__(256) void stage1_kernel(
    const float* __restrict__ frames, const float* __restrict__ attrs,
    const int* __restrict__ aaidx, const float* __restrict__ cen1,
    const float* __restrict__ prec1, const int* __restrict__ idx32,
    u16* __restrict__ outer) {
  __shared__ float sCoord[4 * 16 * 8];
  __shared__ float sAttrT[4 * 20 * 16];  // [pt][h][n]
  __shared__ float sG1T[4 * 32 * 17];    // [pt][g][n], pitch 17
  const int tid = threadIdx.x;
  const int pt = tid >> 6, lane = tid & 63;
  const int pid = blockIdx.x * 4 + pt;
  const int b = pid >> 11;
  const int g = lane & 31;

  float pr[7][7], cn[7];
#pragma unroll
  for (int d = 0; d < 7; d++) {
    cn[d] = cen1[d * 32 + g];
#pragma unroll
    for (int kk = 0; kk < 7; kk++) pr[d][kk] = prec1[(d * 7 + kk) * 32 + g];
  }

  if (lane < 16) {
    int n = lane;
    int j = idx32[pid * 32 + n];
    int jg = b * NL + j;
    const float* fs = frames + (size_t)pid * 12;
    const float* fj = frames + (size_t)jg * 12;
    float4 A0 = *(const float4*)(fs);
    float4 A1 = *(const float4*)(fs + 4);
    float4 A2 = *(const float4*)(fs + 8);
    float4 B0 = *(const float4*)(fj);
    float4 B2 = *(const float4*)(fj + 8);
    float dx = B0.x - A0.x, dy = B0.y - A0.y, dzc = B0.z - A0.z;
    float a0x = A0.w, a0y = A1.x, a0z = A1.y;
    float a1x = A1.z, a1y = A1.w, a1z = A2.x;
    float a2x = A2.y, a2y = A2.z, a2z = A2.w;  // z_i == axes[2]
    float zjx = B2.y, zjy = B2.z, zjz = B2.w;
    float dd = dx * dx + dy * dy + dzc * dzc + 1e-12f;
    float dist = sqrtf(dd);
    float e0 = dx * a0x + dy * a0y + dzc * a0z;
    float e1 = dx * a1x + dy * a1y + dzc * a1z;
    float e2 = dx * a2x + dy * a2y + dzc * a2z;
    float zz = a2x * zjx + a2y * zjy + a2z * zjz;
    float dzv = (dx * zjx + dy * zjy + dzc * zjz) / dist;
    float zdv = (a2x * dx + a2y * dy + a2z * dzc) / dist;
    float si = (float)aaidx[pid];
    float sj = (float)aaidx[jg];
    float idist = fminf(fabsf(sj - si), 8.0f);
    float* cr = sCoord + pt * 128 + n * 8;
    cr[0] = e0; cr[1] = e1; cr[2] = e2; cr[3] = idist;
    cr[4] = zz; cr[5] = dzv; cr[6] = zdv;
    const float* ar = attrs + (size_t)jg * 20;
    float4 q0 = *(const float4*)(ar);
    float4 q1 = *(const float4*)(ar + 4);
    float4 q2 = *(const float4*)(ar + 8);
    float4 q3 = *(const float4*)(ar + 12);
    float4 q4 = *(const float4*)(ar + 16);
    float av[20] = {q0.x, q0.y, q0.z, q0.w, q1.x, q1.y, q1.z, q1.w,
                    q2.x, q2.y, q2.z, q2.w, q3.x, q3.y, q3.z, q3.w,
                    q4.x, q4.y, q4.z, q4.w};
#pragma unroll
    for (int h = 0; h < 20; h++) sAttrT[pt * 320 + h * 16 + n] = av[h];
  }
  __syncthreads();
  {
    const int nh = lane >> 5;
#pragma unroll
    for (int i = 0; i < 8; i++) {
      int n = nh * 8 + i;
      const float* cr = sCoord + pt * 128 + n * 8;
      float df[7];
#pragma unroll
      for (int d = 0; d < 7; d++) df[d] = cr[d] - cn[d];
      float s = 0.0f;
#pragma unroll
      for (int kk = 0; kk < 7; kk++) {
        float y = 0.0f;
#pragma unroll
        for (int d = 0; d < 7; d++) y = fmaf(df[d], pr[d][kk], y);
        s = fmaf(y, y, s);
      }
      sG1T[pt * 544 + g * 17 + n] = __expf(-0.5f * s);
    }
  }
  __syncthreads();
  {
    const int hg = lane >> 5;
    float g16[16];
#pragma unroll
    for (int n = 0; n < 16; n++) g16[n] = sG1T[pt * 544 + g * 17 + n];
    u32* orow = (u32*)(outer + (size_t)pid * 640) + (g * 20 + hg * 10) / 2;
#pragma unroll
    for (int i = 0; i < 5; i++) {
      int h0 = hg * 10 + i * 2, h1 = h0 + 1;
      float a0 = 0.f, a1 = 0.f;
#pragma unroll
      for (int c = 0; c < 4; c++) {
        float4 v0 = *(float4*)&sAttrT[pt * 320 + h0 * 16 + c * 4];
        float4 v1 = *(float4*)&sAttrT[pt * 320 + h1 * 16 + c * 4];
        a0 = fmaf(v0.x, g16[c * 4 + 0], a0);
        a0 = fmaf(v0.y, g16[c * 4 + 1], a0);
        a0 = fmaf(v0.z, g16[c * 4 + 2], a0);
        a0 = fmaf(v0.w, g16[c * 4 + 3], a0);
        a1 = fmaf(v1.x, g16[c * 4 + 0], a1);
        a1 = fmaf(v1.y, g16[c * 4 + 1], a1);
        a1 = fmaf(v1.z, g16[c * 4 + 2], a1);
        a1 = fmaf(v1.w, g16[c * 4 + 3], a1);
      }
      orow[i] = (u32)to_bf16(a0) | ((u32)to_bf16(a1) << 16);
    }
  }
}

// ---------------------------------------------------------------------------
// Kernel C: bf16 MFMA GEMM, full-K single-barrier variant.  [validated r4]
// grid = 512 (tile 32 points x 128 outs), block = 256 (4 waves).
// head8 layout per point: [catt, nf0, nf1, -, beta, satt, -, -]
// ---------------------------------------------------------------------------
__global__ __launch_bounds__(256) void gemm_kernel(
    const u16* __restrict__ outer,  // [16384][640] bf16
    const u16* __restrict__ opWt,   // [128][640] bf16 (o-major)
    const float* __restrict__ opB,
    const u16* __restrict__ embWt,  // [32][128] bf16 (j-major)
    const float* __restrict__ embB,
    const float* __restrict__ w5,   // [32][8] packed head weights
    const float* __restrict__ b5,   // [8] head biases
    float* __restrict__ head8) {
  __shared__ char smem[40960];
  const int tid = threadIdx.x;
  const int w = tid >> 6, lane = tid & 63;
  const int p0 = blockIdx.x * 32;
  const int lr = lane >> 3, lc = lane & 7;
  const int gsw = lc ^ lr;  // swizzled fetch group for A staging
  const int m = lane & 31, kh = lane >> 5;

  f32x16 acc;
#pragma unroll
  for (int r = 0; r < 16; r++) acc[r] = 0.f;

  const u16* gA = outer + (size_t)(p0 + w * 8 + lr) * 640 + gsw * 8;
#pragma unroll
  for (int cc = 0; cc < 10; cc++)
    gload_lds16(gA + cc * 64, smem + cc * 4096 + w * 1024);
  __syncthreads();

  const u16* gB = opWt + (size_t)(w * 32 + m) * 640;
#pragma unroll
  for (int cc = 0; cc < 10; cc++) {
#pragma unroll
    for (int s = 0; s < 4; s++) {
      int pg = (s * 2 + kh) ^ (m & 7);
      bf16x8 av = *(bf16x8*)(smem + cc * 4096 + m * 128 + pg * 16);
      bf16x8 bv = *(const bf16x8*)(gB + cc * 64 + s * 16 + kh * 8);
      acc = __builtin_amdgcn_mfma_f32_32x32x16_bf16(av, bv, acc, 0, 0, 0);
    }
  }
  __syncthreads();  // all waves done reading A before fTile overwrites it

  // ---- epilogue: bias+relu -> bf16 fTile (smem 0..8192, swizzled) ----
  const int o = w * 32 + m;
  float bo = opB[o];
#pragma unroll
  for (int i = 0; i < 2; i++) {
    int j = w * 8 + i * 4 + (lane >> 4);
    int ge = (lane & 15) ^ (j & 7);
    gload_lds16(embWt + j * 128 + ge * 8, smem + 8192 + w * 2048 + i * 1024);
  }
  u16* sFb = (u16*)smem;
#pragma unroll
  for (int r = 0; r < 16; r++) {
    int mm = (r & 3) + 8 * (r >> 2) + 4 * kh;
    float v = fmaxf(acc[r] + bo, 0.f);
    int pg = (o >> 3) ^ (mm & 7);
    sFb[mm * 128 + pg * 8 + (o & 7)] = to_bf16(v);
  }
  __syncthreads();

  f32x16 acc2;
#pragma unroll
  for (int r = 0; r < 16; r++) acc2[r] = 0.f;
#pragma unroll
  for (int t2 = 0; t2 < 2; t2++) {
    int gg = (w * 2 + t2) * 2 + kh;
    int pg = gg ^ (m & 7);
    bf16x8 av = *(bf16x8*)(smem + m * 256 + pg * 16);
    bf16x8 bv = *(bf16x8*)(smem + 8192 + m * 256 + pg * 16);
    acc2 = __builtin_amdgcn_mfma_f32_32x32x16_bf16(av, bv, acc2, 0, 0, 0);
  }
  float* scr = (float*)(smem + 16384) + w * 1024;
#pragma unroll
  for (int r = 0; r < 16; r++) {
    int mm = (r & 3) + 8 * (r >> 2) + 4 * kh;
    scr[mm * 32 + m] = acc2[r];
  }
  __syncthreads();

  {
    float* sc = (float*)(smem + 16384);
    int i4 = tid * 4;
    float4 v0 = *(float4*)(sc + i4);
    float4 v1 = *(float4*)(sc + 1024 + i4);
    float4 v2 = *(float4*)(sc + 2048 + i4);
    float4 v3 = *(float4*)(sc + 3072 + i4);
    int pp = tid >> 3, j0 = (tid & 7) * 4;
    float4 eb = *(const float4*)(embB + j0);
    float4 e;
    e.x = fmaxf(v0.x + v1.x + v2.x + v3.x + eb.x, 0.f);
    e.y = fmaxf(v0.y + v1.y + v2.y + v3.y + eb.y, 0.f);
    e.z = fmaxf(v0.z + v1.z + v2.z + v3.z + eb.z, 0.f);
    e.w = fmaxf(v0.w + v1.w + v2.w + v3.w + eb.w, 0.f);
    *(float4*)((float*)smem + pp * 36 + j0) = e;
  }
  __syncthreads();

  if (tid < 160) {
    int h = tid >> 5, p = tid & 31;
    const float* sE = (const float*)smem + p * 36;
    float a = b5[h];
#pragma unroll
    for (int j = 0; j < 32; j++) a = fmaf(sE[j], w5[j * 8 + h], a);
    a = fmaxf(a, 0.f);
    int slot = (h < 2) ? (h + 4) : (h - 2);
    head8[(size_t)(p0 + p) * 8 + slot] = a;
  }
}

// ---------------------------------------------------------------------------
// Kernel E: stage-2 coords + gaussians + gw + softmax attention -> out.
// block = 256 (4 points x 64 lanes), grid = 4096.  [validated round 4]
// ---------------------------------------------------------------------------
__global__ __launch_bounds__(256) void stage2_kernel(
    const float* __restrict__ frames, const int* __restrict__ aaidx,
    const float* __restrict__ cen2, const float* __restrict__ prec2,
    const float* __restrict__ emb2W, const float* __restrict__ emb2B,
    const int* __restrict__ idx32, const float* __restrict__ head8,
    float* __restrict__ out) {
  __shared__ float sCoord[4 * 32 * 5];
  __shared__ float sG2[4 * 32 * 33];
  const int tid = threadIdx.x;
  const int pt = tid >> 6, lane = tid & 63;
  const int pid = blockIdx.x * 4 + pt;
  const int b = pid >> 11;
  const int g = lane & 31;

  float pr[5][5], cn[5];
#pragma unroll
  for (int d = 0; d < 5; d++) {
    cn[d] = cen2[d * 32 + g];
#pragma unroll
    for (int kk = 0; kk < 5; kk++) pr[d][kk] = prec2[(d * 5 + kk) * 32 + g];
  }

  float4 hv = make_float4(0.f, 0.f, 0.f, 0.f);
  float betaS = 0.f, sattS = 0.f;
  if (lane < 32) {
    int n = lane;
    int j = idx32[pid * 32 + n];
    int jg = b * NL + j;
    const float* fs = frames + (size_t)pid * 12;
    const float* fj = frames + (size_t)jg * 12;
    float4 A0 = *(const float4*)(fs);
    float4 A2 = *(const float4*)(fs + 8);
    float4 B0 = *(const float4*)(fj);
    float4 B2 = *(const float4*)(fj + 8);
    float dx = B0.x - A0.x, dy = B0.y - A0.y, dzc = B0.z - A0.z;
    float a2x = A2.y, a2y = A2.z, a2z = A2.w;  // z_i
    float zjx = B2.y, zjy = B2.z, zjz = B2.w;
    float dd = dx * dx + dy * dy + dzc * dzc + 1e-12f;
    float dist = sqrtf(dd);
    float zz = a2x * zjx + a2y * zjy + a2z * zjz;
    float dzv = (dx * zjx + dy * zjy + dzc * zjz) / dist;
    float zdv = (a2x * dx + a2y * dy + a2z * dzc) / dist;
    float si = (float)aaidx[pid];
    float sj = (float)aaidx[jg];
    float idist = fminf(fabsf(sj - si), 8.0f);
    float* cr = sCoord + pt * 160 + n * 5;
    cr[0] = dist; cr[1] = zz; cr[2] = dzv; cr[3] = zdv; cr[4] = idist;
    hv = *(const float4*)(head8 + (size_t)jg * 8);
    betaS = head8[(size_t)pid * 8 + 4];
    sattS = head8[(size_t)pid * 8 + 5];
  }
  __syncthreads();
  {
    const int nh = lane >> 5;
#pragma unroll
    for (int i = 0; i < 16; i++) {
      int n = nh * 16 + i;
      const float* cr = sCoord + pt * 160 + n * 5;
      float df[5];
#pragma unroll
      for (int d = 0; d < 5; d++) df[d] = cr[d] - cn[d];
      float s = 0.0f;
#pragma unroll
      for (int kk = 0; kk < 5; kk++) {
        float y = 0.0f;
#pragma unroll
        for (int d = 0; d < 5; d++) y = fmaf(df[d], pr[d][kk], y);
        s = fmaf(y, y, s);
      }
      sG2[pt * 1056 + n * 33 + g] = __expf(-0.5f * s);
    }
  }
  __syncthreads();
  if (lane < 32) {
    int n = lane;
    float gw = emb2B[0];
#pragma unroll 8
    for (int gg = 0; gg < 32; gg++)
      gw = fmaf(sG2[pt * 1056 + n * 33 + gg], emb2W[gg], gw);
    gw = fmaxf(gw, 0.0f);
    float e = (n == 0) ? sattS : hv.x;
    float logit = betaS * e;
    float mx = logit;
#pragma unroll
    for (int d = 1; d < 32; d <<= 1) mx = fmaxf(mx, __shfl_xor(mx, d, 64));
    float wv = gw * __expf(logit - mx);
    float S = wv;
#pragma unroll
    for (int d = 1; d < 32; d <<= 1) S += __shfl_xor(S, d, 64);
    float a = wv / (S + 1e-6f);
    float o0 = a * hv.y, o1 = a * hv.z;
#pragma unroll
    for (int d = 1; d < 32; d <<= 1) {
      o0 += __shfl_xor(o0, d, 64);
      o1 += __shfl_xor(o1, d, 64);
    }
    if (n == 0) {
      out[pid * 2 + 0] = o0;
      out[pid * 2 + 1] = o1;
    }
  }
}

// ---------------------------------------------------------------------------
extern "C" void kernel_launch(void* const* d_in, const int* in_sizes, int n_in,
                              void* d_out, int out_size, void* d_ws, size_t ws_size,
                              hipStream_t stream) {
  const float* attrs = (const float*)d_in[0];
  const float* frames = (const float*)d_in[1];
  const int* aaidx = (const int*)d_in[2];
  const float* cen1 = (const float*)d_in[3];
  const float* prec1 = (const float*)d_in[4];
  const float* opW = (const float*)d_in[5];
  const float* opB = (const float*)d_in[6];
  const float* embW = (const float*)d_in[7];
  const float* embB = (const float*)d_in[8];
  const float* betaW = (const float*)d_in[9];
  const float* betaB = (const float*)d_in[10];
  const float* sattW = (const float*)d_in[11];
  const float* sattB = (const float*)d_in[12];
  const float* cattW = (const float*)d_in[13];
  const float* cattB = (const float*)d_in[14];
  const float* nodW = (const float*)d_in[15];
  const float* nodB = (const float*)d_in[16];
  const float* cen2 = (const float*)d_in[17];
  const float* prec2 = (const float*)d_in[18];
  const float* emb2W = (const float*)d_in[19];
  const float* emb2B = (const float*)d_in[20];
  float* out = (float*)d_out;

  char* ws = (char*)d_ws;
  int* idx32 = (int*)ws;                              // 2 MiB
  u16* outer_bf = (u16*)(ws + 2097152);               // 16384*640*2 = 20 MiB
  float* head8 = (float*)(ws + 23068672);             // 512 KiB
  u16* opWt = (u16*)(ws + 23592960);                  // 160 KiB
  u16* embWt = (u16*)(ws + 23756800);                 // 8 KiB
  float* w5 = (float*)(ws + 23764992);                // 1 KiB
  float* b5 = (float*)(ws + 23766016);                // 32 B

  knn_prep_kernel<<<dim3(2059), dim3(512), 0, stream>>>(
      frames, idx32, opW, embW, betaW, sattW, cattW, nodW, betaB, sattB,
      cattB, nodB, opWt, embWt, w5, b5);
  stage1_kernel<<<dim3(4096), dim3(256), 0, stream>>>(frames, attrs, aaidx, cen1,
                                                      prec1, idx32, outer_bf);
  gemm_kernel<<<dim3(512), dim3(256), 0, stream>>>(outer_bf, opWt, opB, embWt,
                                                   embB, w5, b5, head8);
  stage2_kernel<<<dim3(4096), dim3(256), 0, stream>>>(frames, aaidx, cen2, prec2,
                                                      emb2W, emb2B, idx32, head8, out);
}